// Round 8
// baseline (18157.877 us; speedup 1.0000x reference)
//
#include <hip/hip_runtime.h>
#include <hip/hip_bf16.h>
#include <math.h>

// Problem constants
#define NN   4
#define MM   2048
#define CC   512
#define HH   8
#define DD   64
#define TK   16
#define NMR  8192      // NN*MM
#define QKVC 1536      // 3*CC

// f32(512**-0.5): NEP50 casts the python-float scale to f32 before the ufunc mul
#define SCALE32 ((float)0.044194173824159216)

typedef float v2f __attribute__((ext_vector_type(2)));

// strict f32 multiply that cannot be contracted into a downstream FMA
__device__ __forceinline__ float fmul_nf(float a, float b) {
  float p = a * b;
  asm("" : "+v"(p));
  return p;
}

// "a strictly precedes b" in top-k order (value desc, index asc on ties) — f32 values
__device__ __forceinline__ bool gtpf(float v1, int i1, float v2, int i2) {
  return (v1 > v2) || (v1 == v2 && i1 < i2);
}

// ---------------- Kernel 1: conv + QKV GEMM, f32 np-mimicry --------------------------
// Handles `rows = gridDim.x*64` rows (8192 batched, 2048 per-n fallback).
// x2 = x + (((x[-1]*w0 + x[0]*w1) + x[1]*w2) + cb)   [ufunc order, no FMA]
// q/k/v = x2 @ w_qkv (+bias): f32, sequential k=0..511, FMA per step.
__global__ __launch_bounds__(256) void gemm_conv_qkv_kernel(
    const float* __restrict__ x,
    const float* __restrict__ cw,
    const float* __restrict__ cb,
    const float* __restrict__ wqkv,
    const float* __restrict__ bqkv,
    float* __restrict__ Q, float* __restrict__ K, float* __restrict__ V)
{
  __shared__ float As[16][68];    // [k][row], x2 tile
  __shared__ float Bs[16][68];    // [k][col], weights
  __shared__ float cwb[CC*4];     // [c*4+{0,1,2}]=taps, [c*4+3]=bias

  int tid = threadIdx.x;
  for (int i = tid; i < CC; i += 256) {
    cwb[i*4+0] = cw[i*3+0];
    cwb[i*4+1] = cw[i*3+1];
    cwb[i*4+2] = cw[i*3+2];
    cwb[i*4+3] = cb[i];
  }

  int bm = blockIdx.x, bn = blockIdx.y;
  int tx = tid & 15, ty = tid >> 4;
  int ar = tid >> 2;               // tile row 0..63
  int ak = (tid & 3) << 2;         // k offset 0,4,8,12
  int brow = tid >> 4;             // 0..15
  int bcol = (tid & 15) << 2;      // 0..60
  int row = bm*64 + ar;            // global row (any multiple-of-2048 batch)
  int m = row & (MM - 1);          // position within sequence (conv boundaries)
  const float* xp = x + (size_t)row*CC;
  const float* wp = wqkv + (size_t)brow*QKVC + bn*64 + bcol;

  float acc[4][4];
  #pragma unroll
  for (int i=0;i<4;i++)
    #pragma unroll
    for (int j=0;j<4;j++) acc[i][j]=0.f;

  for (int kt = 0; kt < CC/16; ++kt) {
    int c0 = kt*16 + ak;
    float4 x0  = *(const float4*)(xp + c0);
    float4 xm1 = make_float4(0.f,0.f,0.f,0.f);
    float4 xp1 = make_float4(0.f,0.f,0.f,0.f);
    if (m > 0)      xm1 = *(const float4*)(xp - CC + c0);
    if (m < MM - 1) xp1 = *(const float4*)(xp + CC + c0);
    float4 wv = *(const float4*)(wp + (size_t)kt*16*QKVC);

    __syncthreads();
    {
      const float xe[4]  = {x0.x,  x0.y,  x0.z,  x0.w};
      const float xme[4] = {xm1.x, xm1.y, xm1.z, xm1.w};
      const float xpe[4] = {xp1.x, xp1.y, xp1.z, xp1.w};
      #pragma unroll
      for (int e = 0; e < 4; ++e) {
        int c = c0 + e;
        float p0 = fmul_nf(xme[e], cwb[c*4+0]);
        float p1 = fmul_nf(xe[e],  cwb[c*4+1]);
        float p2 = fmul_nf(xpe[e], cwb[c*4+2]);
        float s  = p0 + p1;
        s = s + p2;
        s = s + cwb[c*4+3];
        As[ak+e][ar] = xe[e] + s;                 // x2 = x + pos
      }
    }
    *(float4*)&Bs[brow][bcol] = wv;
    __syncthreads();

    #pragma unroll
    for (int kk = 0; kk < 16; ++kk) {
      float4 a4 = *(const float4*)&As[kk][ty<<2];
      float4 b4 = *(const float4*)&Bs[kk][tx<<2];
      const float ae[4] = {a4.x, a4.y, a4.z, a4.w};
      const float be[4] = {b4.x, b4.y, b4.z, b4.w};
      #pragma unroll
      for (int i=0;i<4;i++)
        #pragma unroll
        for (int j=0;j<4;j++)
          acc[i][j] = __builtin_fmaf(ae[i], be[j], acc[i][j]);
    }
  }

  int orow = bm*64 + (ty<<2);
  int seg  = bn >> 3;                       // 0=q, 1=k, 2=v
  float* dst = (seg==0) ? Q : ((seg==1) ? K : V);
  int col  = (bn & 7)*64 + (tx<<2);
  float bb[4];
  #pragma unroll
  for (int j=0;j<4;j++) bb[j] = bqkv[bn*64 + (tx<<2) + j];
  #pragma unroll
  for (int i=0;i<4;i++) {
    float4 o = make_float4(acc[i][0]+bb[0], acc[i][1]+bb[1],
                           acc[i][2]+bb[2], acc[i][3]+bb[3]);
    *(float4*)&dst[(size_t)(orow+i)*CC + col] = o;
  }
}

// ---------------- Kernel 2: f32 logits + top-16 + softmax + V-gather -----------------
// Grid: (#batches)*HH*64 blocks; block 256 = 32 queries x (16 key-slots x 2 q/thread).
// bq -> n = bq>>9 (0 in per-n fallback), h = (bq>>6)&7, qt = bq&63.
// Per-logit FP chain identical to r6/r7: t ascending, separate mul+add.
__global__ __launch_bounds__(256) void route_attn_kernel(
    const float* __restrict__ Q,
    const float* __restrict__ K,
    const float* __restrict__ V,
    float* __restrict__ attn)
{
  __shared__ float qs[32][68];    // q*scale32 (f32-rounded)
  __shared__ float ks[128][68];   // staged k-tile
  int bq = blockIdx.x;
  int n = bq >> 9, h = (bq >> 6) & 7, qt = bq & 63;
  int tid = threadIdx.x;
  int s = tid & 15, qi = tid >> 4;   // thread owns queries qi and qi+16
  size_t nbase = (size_t)n * MM * CC;

  // stage q tile (32 rows x 16 float4), scale applied once in f32
  #pragma unroll
  for (int rep = 0; rep < 2; ++rep) {
    int idx = tid + (rep<<8);
    int r = idx >> 4, c4 = idx & 15;
    const float* p = Q + nbase + (size_t)(qt*32 + r)*CC + h*DD + (c4<<2);
    float4 v = *(const float4*)p;
    qs[r][(c4<<2)+0] = v.x * SCALE32;
    qs[r][(c4<<2)+1] = v.y * SCALE32;
    qs[r][(c4<<2)+2] = v.z * SCALE32;
    qs[r][(c4<<2)+3] = v.w * SCALE32;
  }

  float lvA[16], lvB[16]; int liA[16], liB[16];
  #pragma unroll
  for (int i=0;i<16;i++){ lvA[i]=-INFINITY; liA[i]=i; lvB[i]=-INFINITY; liB[i]=i; }

  for (int kt = 0; kt < 16; ++kt) {      // 16 tiles x 128 keys
    __syncthreads();
    #pragma unroll
    for (int rep = 0; rep < 8; ++rep) {
      int idx = tid + (rep<<8);          // 0..2047
      int r = idx >> 4, c4 = idx & 15;
      *(float4*)&ks[r][c4<<2] =
          *(const float4*)(K + nbase + (size_t)(kt*128 + r)*CC + h*DD + (c4<<2));
    }
    __syncthreads();

    float accA[8], accB[8];
    #pragma unroll
    for (int j=0;j<8;j++){ accA[j]=0.f; accB[j]=0.f; }

    #pragma unroll
    for (int t4 = 0; t4 < 16; ++t4) {    // dims ascending: t = 4*t4 + {0,1,2,3}
      float4 qa = *(const float4*)&qs[qi][t4<<2];
      float4 qb = *(const float4*)&qs[qi+16][t4<<2];
      v2f qa01 = {qa.x, qa.y}, qa23 = {qa.z, qa.w};
      v2f qb01 = {qb.x, qb.y}, qb23 = {qb.z, qb.w};
      #pragma unroll
      for (int j = 0; j < 8; ++j) {
        float4 kv = *(const float4*)&ks[s + (j<<4)][t4<<2];
        v2f k01 = {kv.x, kv.y}, k23 = {kv.z, kv.w};
        // vector muls (packable to v_pk_mul_f32); each product individually
        // rounded f32; barrier on scalars blocks FMA contraction; adds stay
        // sequential x,y,z,w — bit-identical chain to r6/r7.
        v2f pa0 = qa01 * k01, pa1 = qa23 * k23;
        v2f pb0 = qb01 * k01, pb1 = qb23 * k23;
        float a0 = pa0.x, a1 = pa0.y, a2 = pa1.x, a3 = pa1.y;
        float b0 = pb0.x, b1 = pb0.y, b2 = pb1.x, b3 = pb1.y;
        asm("" : "+v"(a0), "+v"(a1), "+v"(a2), "+v"(a3),
                 "+v"(b0), "+v"(b1), "+v"(b2), "+v"(b3));
        accA[j] = ((((accA[j] + a0) + a1) + a2) + a3);
        accB[j] = ((((accB[j] + b0) + b1) + b2) + b3);
      }
    }

    // streaming inserts; key idx = kt*128 + s + 16j ascending per thread, so on
    // exact value tie the incumbent (smaller idx) correctly wins via strict >
    #pragma unroll
    for (int j=0;j<8;j++) {
      int kidx = kt*128 + s + (j<<4);
      float v = accA[j];
      if (v > lvA[15]) {
        lvA[15] = v; liA[15] = kidx;
        #pragma unroll
        for (int p = 15; p >= 1; --p) {
          if (gtpf(lvA[p], liA[p], lvA[p-1], liA[p-1])) {
            float tv = lvA[p]; lvA[p] = lvA[p-1]; lvA[p-1] = tv;
            int   ti = liA[p]; liA[p] = liA[p-1]; liA[p-1] = ti;
          }
        }
      }
      v = accB[j];
      if (v > lvB[15]) {
        lvB[15] = v; liB[15] = kidx;
        #pragma unroll
        for (int p = 15; p >= 1; --p) {
          if (gtpf(lvB[p], liB[p], lvB[p-1], liB[p-1])) {
            float tv = lvB[p]; lvB[p] = lvB[p-1]; lvB[p-1] = tv;
            int   ti = liB[p]; liB[p] = liB[p-1]; liB[p-1] = ti;
          }
        }
      }
    }
  }

  // 16-lane butterfly merge + epilogue, list A then list B
  #pragma unroll
  for (int which = 0; which < 2; ++which) {
    float lv[16]; int li[16];
    #pragma unroll
    for (int i=0;i<16;i++){ lv[i] = which ? lvB[i] : lvA[i];
                            li[i] = which ? liB[i] : liA[i]; }
    #pragma unroll
    for (int off = 1; off < 16; off <<= 1) {
      float nv[16]; int ni[16];
      #pragma unroll
      for (int i = 0; i < 16; ++i) {       // half-cleaner
        float bv = __shfl_xor(lv[15 - i], off);
        int   bi = __shfl_xor(li[15 - i], off);
        bool g = gtpf(lv[i], li[i], bv, bi);
        nv[i] = g ? lv[i] : bv;
        ni[i] = g ? li[i] : bi;
      }
      #pragma unroll
      for (int d = 8; d >= 1; d >>= 1) {   // bitonic -> sorted desc
        #pragma unroll
        for (int i = 0; i < 16; ++i) {
          if ((i & d) == 0) {
            if (!gtpf(nv[i], ni[i], nv[i+d], ni[i+d])) {
              float tv = nv[i]; nv[i] = nv[i+d]; nv[i+d] = tv;
              int   ti = ni[i]; ni[i] = ni[i+d]; ni[i+d] = ti;
            }
          }
        }
      }
      #pragma unroll
      for (int i = 0; i < 16; ++i) { lv[i] = nv[i]; li[i] = ni[i]; }
    }

    // softmax (f32) + V gather: lane s handles dims [4s, 4s+4)
    float e[16]; float Z = 0.f;
    float mx = lv[0];                 // sorted desc -> max
    #pragma unroll
    for (int i=0;i<16;i++){ e[i] = expf(lv[i]-mx); Z += e[i]; }
    float invZ = 1.f / Z;
    float4 o = make_float4(0.f,0.f,0.f,0.f);
    #pragma unroll
    for (int i=0;i<16;i++) {
      int ki = li[i] & (MM - 1);          // masked: can never read wild
      const float* vp = V + nbase + (size_t)ki*CC + h*DD + (s<<2);
      float4 vv = *(const float4*)vp;
      float w = e[i]*invZ;
      o.x += w*vv.x; o.y += w*vv.y; o.z += w*vv.z; o.w += w*vv.w;
    }
    int qrow = qt*32 + qi + (which ? 16 : 0);
    *(float4*)&attn[nbase + (size_t)qrow*CC + h*DD + (s<<2)] = o;
  }
}

// ---------------- Kernel 3: f32 GEMM out = attn @ w_o + b_o -> f32 -------------------
__global__ __launch_bounds__(256) void gemm_out_kernel(
    const float* __restrict__ A,
    const float* __restrict__ W,
    const float* __restrict__ bias,
    float* __restrict__ O,
    int ncols)
{
  __shared__ float As[16][68];
  __shared__ float Bs[16][68];
  int tid = threadIdx.x;
  int bm = blockIdx.x, bn = blockIdx.y;
  int tx = tid & 15, ty = tid >> 4;
  int ar = tid >> 2;
  int ak = (tid & 3) << 2;
  int brow = tid >> 4;
  int bcol = (tid & 15) << 2;
  const float* Ap = A + (size_t)(bm*64 + ar)*CC + ak;
  const float* Wp = W + (size_t)brow*ncols + bn*64 + bcol;

  float acc[4][4];
  #pragma unroll
  for (int i=0;i<4;i++)
    #pragma unroll
    for (int j=0;j<4;j++) acc[i][j]=0.f;

  for (int kt = 0; kt < CC/16; ++kt) {
    float4 av = *(const float4*)(Ap + kt*16);
    float4 wv = *(const float4*)(Wp + (size_t)kt*16*ncols);
    __syncthreads();
    As[ak+0][ar]=av.x; As[ak+1][ar]=av.y; As[ak+2][ar]=av.z; As[ak+3][ar]=av.w;
    *(float4*)&Bs[brow][bcol] = wv;
    __syncthreads();
    #pragma unroll
    for (int kk = 0; kk < 16; ++kk) {
      float4 a4 = *(const float4*)&As[kk][ty<<2];
      float4 b4 = *(const float4*)&Bs[kk][tx<<2];
      const float ae[4] = {a4.x, a4.y, a4.z, a4.w};
      const float be[4] = {b4.x, b4.y, b4.z, b4.w};
      #pragma unroll
      for (int i=0;i<4;i++)
        #pragma unroll
        for (int j=0;j<4;j++)
          acc[i][j] = __builtin_fmaf(ae[i], be[j], acc[i][j]);
    }
  }
  int row = bm*64 + (ty<<2);
  int col = bn*64 + (tx<<2);
  float bb[4];
  #pragma unroll
  for (int j=0;j<4;j++) bb[j] = bias[col+j];
  #pragma unroll
  for (int i=0;i<4;i++) {
    float4 o = make_float4(acc[i][0]+bb[0], acc[i][1]+bb[1],
                           acc[i][2]+bb[2], acc[i][3]+bb[3]);
    *(float4*)&O[(size_t)(row+i)*ncols + col] = o;
  }
}

// ---------------- launch --------------------------------------------------------------
extern "C" void kernel_launch(void* const* d_in, const int* in_sizes, int n_in,
                              void* d_out, int out_size, void* d_ws, size_t ws_size,
                              hipStream_t stream) {
  (void)in_sizes; (void)n_in; (void)out_size;
  const float* x      = (const float*)d_in[0];
  const float* conv_w = (const float*)d_in[1];
  const float* conv_b = (const float*)d_in[2];
  const float* w_qkv  = (const float*)d_in[3];
  const float* b_qkv  = (const float*)d_in[4];
  const float* w_o    = (const float*)d_in[5];
  const float* b_o    = (const float*)d_in[6];
  float* out = (float*)d_out;

  size_t perbuf_b = (size_t)NMR * CC;               // batched buffer elems
  bool batched = ws_size >= 4 * perbuf_b * sizeof(float);   // 64 MB

  if (batched) {
    float* Qb = (float*)d_ws;
    float* Kb = Qb + perbuf_b;
    float* Vb = Kb + perbuf_b;
    float* at = Vb + perbuf_b;
    gemm_conv_qkv_kernel<<<dim3(NMR/64, QKVC/64), 256, 0, stream>>>(
        x, conv_w, conv_b, w_qkv, b_qkv, Qb, Kb, Vb);
    route_attn_kernel<<<NN*HH*(MM/32), 256, 0, stream>>>(Qb, Kb, Vb, at);
    gemm_out_kernel<<<dim3(NMR/64, CC/64), 256, 0, stream>>>(at, w_o, b_o, out, CC);
  } else {
    size_t perbuf = (size_t)MM * CC;                // per-n fallback (16 MB)
    float* Qb = (float*)d_ws;
    float* Kb = Qb + perbuf;
    float* Vb = Kb + perbuf;
    float* at = Vb + perbuf;
    for (int n = 0; n < NN; ++n) {
      const float* xn = x + (size_t)n*MM*CC;
      gemm_conv_qkv_kernel<<<dim3(MM/64, QKVC/64), 256, 0, stream>>>(
          xn, conv_w, conv_b, w_qkv, b_qkv, Qb, Kb, Vb);
      route_attn_kernel<<<HH*(MM/32), 256, 0, stream>>>(Qb, Kb, Vb, at);
      gemm_out_kernel<<<dim3(MM/64, CC/64), 256, 0, stream>>>(
          at, w_o, b_o, out + (size_t)n*MM*CC, CC);
    }
  }
}

// Round 9
// 1185.725 us; speedup vs baseline: 15.3137x; 15.3137x over previous
//
#include <hip/hip_runtime.h>
#include <hip/hip_bf16.h>
#include <math.h>

// Problem constants
#define NN   4
#define MM   2048
#define CC   512
#define HH   8
#define DD   64
#define TK   16
#define NMR  8192      // NN*MM
#define QKVC 1536      // 3*CC

// f32(512**-0.5): NEP50 casts the python-float scale to f32 before the ufunc mul
#define SCALE32 ((float)0.044194173824159216)

// strict f32 multiply that cannot be contracted into a downstream FMA
__device__ __forceinline__ float fmul_nf(float a, float b) {
  float p = a * b;
  asm("" : "+v"(p));
  return p;
}

// "a strictly precedes b" in top-k order (value desc, index asc on ties) — f32 values
__device__ __forceinline__ bool gtpf(float v1, int i1, float v2, int i2) {
  return (v1 > v2) || (v1 == v2 && i1 < i2);
}

// ---------------- Kernel 1: conv + QKV GEMM, f32 np-mimicry --------------------------
// Handles gridDim.x*64 rows (8192 batched / 2048 per-n fallback).
// x2 = x + (((x[-1]*w0 + x[0]*w1) + x[1]*w2) + cb)   [ufunc order, no FMA]
// q/k/v = x2 @ w_qkv (+bias): f32, sequential k=0..511, FMA per step.
__global__ __launch_bounds__(256) void gemm_conv_qkv_kernel(
    const float* __restrict__ x,
    const float* __restrict__ cw,
    const float* __restrict__ cb,
    const float* __restrict__ wqkv,
    const float* __restrict__ bqkv,
    float* __restrict__ Q, float* __restrict__ K, float* __restrict__ V)
{
  __shared__ float As[16][68];    // [k][row], x2 tile
  __shared__ float Bs[16][68];    // [k][col], weights
  __shared__ float cwb[CC*4];     // [c*4+{0,1,2}]=taps, [c*4+3]=bias

  int tid = threadIdx.x;
  for (int i = tid; i < CC; i += 256) {
    cwb[i*4+0] = cw[i*3+0];
    cwb[i*4+1] = cw[i*3+1];
    cwb[i*4+2] = cw[i*3+2];
    cwb[i*4+3] = cb[i];
  }

  int bm = blockIdx.x, bn = blockIdx.y;
  int tx = tid & 15, ty = tid >> 4;
  int ar = tid >> 2;               // tile row 0..63
  int ak = (tid & 3) << 2;         // k offset 0,4,8,12
  int brow = tid >> 4;             // 0..15
  int bcol = (tid & 15) << 2;      // 0..60
  int row = bm*64 + ar;            // global row
  int m = row & (MM - 1);          // position within sequence (conv boundaries)
  const float* xp = x + (size_t)row*CC;
  const float* wp = wqkv + (size_t)brow*QKVC + bn*64 + bcol;

  float acc[4][4];
  #pragma unroll
  for (int i=0;i<4;i++)
    #pragma unroll
    for (int j=0;j<4;j++) acc[i][j]=0.f;

  for (int kt = 0; kt < CC/16; ++kt) {
    int c0 = kt*16 + ak;
    float4 x0  = *(const float4*)(xp + c0);
    float4 xm1 = make_float4(0.f,0.f,0.f,0.f);
    float4 xp1 = make_float4(0.f,0.f,0.f,0.f);
    if (m > 0)      xm1 = *(const float4*)(xp - CC + c0);
    if (m < MM - 1) xp1 = *(const float4*)(xp + CC + c0);
    float4 wv = *(const float4*)(wp + (size_t)kt*16*QKVC);

    __syncthreads();
    {
      const float xe[4]  = {x0.x,  x0.y,  x0.z,  x0.w};
      const float xme[4] = {xm1.x, xm1.y, xm1.z, xm1.w};
      const float xpe[4] = {xp1.x, xp1.y, xp1.z, xp1.w};
      #pragma unroll
      for (int e = 0; e < 4; ++e) {
        int c = c0 + e;
        float p0 = fmul_nf(xme[e], cwb[c*4+0]);
        float p1 = fmul_nf(xe[e],  cwb[c*4+1]);
        float p2 = fmul_nf(xpe[e], cwb[c*4+2]);
        float s  = p0 + p1;
        s = s + p2;
        s = s + cwb[c*4+3];
        As[ak+e][ar] = xe[e] + s;                 // x2 = x + pos
      }
    }
    *(float4*)&Bs[brow][bcol] = wv;
    __syncthreads();

    #pragma unroll
    for (int kk = 0; kk < 16; ++kk) {
      float4 a4 = *(const float4*)&As[kk][ty<<2];
      float4 b4 = *(const float4*)&Bs[kk][tx<<2];
      const float ae[4] = {a4.x, a4.y, a4.z, a4.w};
      const float be[4] = {b4.x, b4.y, b4.z, b4.w};
      #pragma unroll
      for (int i=0;i<4;i++)
        #pragma unroll
        for (int j=0;j<4;j++)
          acc[i][j] = __builtin_fmaf(ae[i], be[j], acc[i][j]);
    }
  }

  int orow = bm*64 + (ty<<2);
  int seg  = bn >> 3;                       // 0=q, 1=k, 2=v
  float* dst = (seg==0) ? Q : ((seg==1) ? K : V);
  int col  = (bn & 7)*64 + (tx<<2);
  float bb[4];
  #pragma unroll
  for (int j=0;j<4;j++) bb[j] = bqkv[bn*64 + (tx<<2) + j];
  #pragma unroll
  for (int i=0;i<4;i++) {
    float4 o = make_float4(acc[i][0]+bb[0], acc[i][1]+bb[1],
                           acc[i][2]+bb[2], acc[i][3]+bb[3]);
    *(float4*)&dst[(size_t)(orow+i)*CC + col] = o;
  }
}

// ---------------- Kernel 2: f32 logits + top-16 + softmax + V-gather -----------------
// EXACT round-7 inner structure (VGPR 72, no spill): rolled t4 loop, scalar fmul_nf.
// Grid: (#batches)*HH*64 blocks; bq -> n = bq>>9, h = (bq>>6)&7, qt = bq&63.
__global__ __launch_bounds__(256) void route_attn_kernel(
    const float* __restrict__ Q,
    const float* __restrict__ K,
    const float* __restrict__ V,
    float* __restrict__ attn)
{
  __shared__ float qs[32][68];    // q*scale32 (f32-rounded)
  __shared__ float ks[128][68];   // staged k-tile
  int bq = blockIdx.x;
  int n = bq >> 9, h = (bq >> 6) & 7, qt = bq & 63;
  int tid = threadIdx.x;
  int s = tid & 15, qi = tid >> 4;   // thread owns queries qi and qi+16
  size_t nbase = (size_t)n * MM * CC;

  // stage q tile (32 rows x 16 float4), scale applied once in f32
  #pragma unroll
  for (int rep = 0; rep < 2; ++rep) {
    int idx = tid + (rep<<8);
    int r = idx >> 4, c4 = idx & 15;
    const float* p = Q + nbase + (size_t)(qt*32 + r)*CC + h*DD + (c4<<2);
    float4 v = *(const float4*)p;
    qs[r][(c4<<2)+0] = v.x * SCALE32;
    qs[r][(c4<<2)+1] = v.y * SCALE32;
    qs[r][(c4<<2)+2] = v.z * SCALE32;
    qs[r][(c4<<2)+3] = v.w * SCALE32;
  }

  float lvA[16], lvB[16]; int liA[16], liB[16];
  #pragma unroll
  for (int i=0;i<16;i++){ lvA[i]=-INFINITY; liA[i]=i; lvB[i]=-INFINITY; liB[i]=i; }

  for (int kt = 0; kt < 16; ++kt) {      // 16 tiles x 128 keys
    __syncthreads();
    #pragma unroll
    for (int rep = 0; rep < 8; ++rep) {
      int idx = tid + (rep<<8);          // 0..2047
      int r = idx >> 4, c4 = idx & 15;
      *(float4*)&ks[r][c4<<2] =
          *(const float4*)(K + nbase + (size_t)(kt*128 + r)*CC + h*DD + (c4<<2));
    }
    __syncthreads();

    float accA[8], accB[8];
    #pragma unroll
    for (int j=0;j<8;j++){ accA[j]=0.f; accB[j]=0.f; }

    for (int t4 = 0; t4 < 16; ++t4) {    // rolled: keeps VGPR pressure low (r7 form)
      float4 qa = *(const float4*)&qs[qi][t4<<2];
      float4 qb = *(const float4*)&qs[qi+16][t4<<2];
      #pragma unroll
      for (int j = 0; j < 8; ++j) {
        float4 kv = *(const float4*)&ks[s + (j<<4)][t4<<2];
        // separate mul+add, sequential in t — bit-identical np-einsum chain
        accA[j] = accA[j] + fmul_nf(qa.x, kv.x);
        accA[j] = accA[j] + fmul_nf(qa.y, kv.y);
        accA[j] = accA[j] + fmul_nf(qa.z, kv.z);
        accA[j] = accA[j] + fmul_nf(qa.w, kv.w);
        accB[j] = accB[j] + fmul_nf(qb.x, kv.x);
        accB[j] = accB[j] + fmul_nf(qb.y, kv.y);
        accB[j] = accB[j] + fmul_nf(qb.z, kv.z);
        accB[j] = accB[j] + fmul_nf(qb.w, kv.w);
      }
    }

    // streaming inserts; key idx = kt*128 + s + 16j ascending per thread, so on
    // exact value tie the incumbent (smaller idx) correctly wins via strict >
    #pragma unroll
    for (int j=0;j<8;j++) {
      int kidx = kt*128 + s + (j<<4);
      float v = accA[j];
      if (v > lvA[15]) {
        lvA[15] = v; liA[15] = kidx;
        #pragma unroll
        for (int p = 15; p >= 1; --p) {
          if (gtpf(lvA[p], liA[p], lvA[p-1], liA[p-1])) {
            float tv = lvA[p]; lvA[p] = lvA[p-1]; lvA[p-1] = tv;
            int   ti = liA[p]; liA[p] = liA[p-1]; liA[p-1] = ti;
          }
        }
      }
      v = accB[j];
      if (v > lvB[15]) {
        lvB[15] = v; liB[15] = kidx;
        #pragma unroll
        for (int p = 15; p >= 1; --p) {
          if (gtpf(lvB[p], liB[p], lvB[p-1], liB[p-1])) {
            float tv = lvB[p]; lvB[p] = lvB[p-1]; lvB[p-1] = tv;
            int   ti = liB[p]; liB[p] = liB[p-1]; liB[p-1] = ti;
          }
        }
      }
    }
  }

  // 16-lane butterfly merge + epilogue, list A then list B
  #pragma unroll
  for (int which = 0; which < 2; ++which) {
    float lv[16]; int li[16];
    #pragma unroll
    for (int i=0;i<16;i++){ lv[i] = which ? lvB[i] : lvA[i];
                            li[i] = which ? liB[i] : liA[i]; }
    #pragma unroll
    for (int off = 1; off < 16; off <<= 1) {
      float nv[16]; int ni[16];
      #pragma unroll
      for (int i = 0; i < 16; ++i) {       // half-cleaner
        float bv = __shfl_xor(lv[15 - i], off);
        int   bi = __shfl_xor(li[15 - i], off);
        bool g = gtpf(lv[i], li[i], bv, bi);
        nv[i] = g ? lv[i] : bv;
        ni[i] = g ? li[i] : bi;
      }
      #pragma unroll
      for (int d = 8; d >= 1; d >>= 1) {   // bitonic -> sorted desc
        #pragma unroll
        for (int i = 0; i < 16; ++i) {
          if ((i & d) == 0) {
            if (!gtpf(nv[i], ni[i], nv[i+d], ni[i+d])) {
              float tv = nv[i]; nv[i] = nv[i+d]; nv[i+d] = tv;
              int   ti = ni[i]; ni[i] = ni[i+d]; ni[i+d] = ti;
            }
          }
        }
      }
      #pragma unroll
      for (int i = 0; i < 16; ++i) { lv[i] = nv[i]; li[i] = ni[i]; }
    }

    // softmax (f32) + V gather: lane s handles dims [4s, 4s+4)
    float e[16]; float Z = 0.f;
    float mx = lv[0];                 // sorted desc -> max
    #pragma unroll
    for (int i=0;i<16;i++){ e[i] = expf(lv[i]-mx); Z += e[i]; }
    float invZ = 1.f / Z;
    float4 o = make_float4(0.f,0.f,0.f,0.f);
    #pragma unroll
    for (int i=0;i<16;i++) {
      int ki = li[i] & (MM - 1);          // masked: can never read wild
      const float* vp = V + nbase + (size_t)ki*CC + h*DD + (s<<2);
      float4 vv = *(const float4*)vp;
      float w = e[i]*invZ;
      o.x += w*vv.x; o.y += w*vv.y; o.z += w*vv.z; o.w += w*vv.w;
    }
    int qrow = qt*32 + qi + (which ? 16 : 0);
    *(float4*)&attn[nbase + (size_t)qrow*CC + h*DD + (s<<2)] = o;
  }
}

// ---------------- Kernel 3: f32 GEMM out = attn @ w_o + b_o -> f32 -------------------
__global__ __launch_bounds__(256) void gemm_out_kernel(
    const float* __restrict__ A,
    const float* __restrict__ W,
    const float* __restrict__ bias,
    float* __restrict__ O,
    int ncols)
{
  __shared__ float As[16][68];
  __shared__ float Bs[16][68];
  int tid = threadIdx.x;
  int bm = blockIdx.x, bn = blockIdx.y;
  int tx = tid & 15, ty = tid >> 4;
  int ar = tid >> 2;
  int ak = (tid & 3) << 2;
  int brow = tid >> 4;
  int bcol = (tid & 15) << 2;
  const float* Ap = A + (size_t)(bm*64 + ar)*CC + ak;
  const float* Wp = W + (size_t)brow*ncols + bn*64 + bcol;

  float acc[4][4];
  #pragma unroll
  for (int i=0;i<4;i++)
    #pragma unroll
    for (int j=0;j<4;j++) acc[i][j]=0.f;

  for (int kt = 0; kt < CC/16; ++kt) {
    float4 av = *(const float4*)(Ap + kt*16);
    float4 wv = *(const float4*)(Wp + (size_t)kt*16*ncols);
    __syncthreads();
    As[ak+0][ar]=av.x; As[ak+1][ar]=av.y; As[ak+2][ar]=av.z; As[ak+3][ar]=av.w;
    *(float4*)&Bs[brow][bcol] = wv;
    __syncthreads();
    #pragma unroll
    for (int kk = 0; kk < 16; ++kk) {
      float4 a4 = *(const float4*)&As[kk][ty<<2];
      float4 b4 = *(const float4*)&Bs[kk][tx<<2];
      const float ae[4] = {a4.x, a4.y, a4.z, a4.w};
      const float be[4] = {b4.x, b4.y, b4.z, b4.w};
      #pragma unroll
      for (int i=0;i<4;i++)
        #pragma unroll
        for (int j=0;j<4;j++)
          acc[i][j] = __builtin_fmaf(ae[i], be[j], acc[i][j]);
    }
  }
  int row = bm*64 + (ty<<2);
  int col = bn*64 + (tx<<2);
  float bb[4];
  #pragma unroll
  for (int j=0;j<4;j++) bb[j] = bias[col+j];
  #pragma unroll
  for (int i=0;i<4;i++) {
    float4 o = make_float4(acc[i][0]+bb[0], acc[i][1]+bb[1],
                           acc[i][2]+bb[2], acc[i][3]+bb[3]);
    *(float4*)&O[(size_t)(row+i)*ncols + col] = o;
  }
}

// ---------------- launch --------------------------------------------------------------
extern "C" void kernel_launch(void* const* d_in, const int* in_sizes, int n_in,
                              void* d_out, int out_size, void* d_ws, size_t ws_size,
                              hipStream_t stream) {
  (void)in_sizes; (void)n_in; (void)out_size;
  const float* x      = (const float*)d_in[0];
  const float* conv_w = (const float*)d_in[1];
  const float* conv_b = (const float*)d_in[2];
  const float* w_qkv  = (const float*)d_in[3];
  const float* b_qkv  = (const float*)d_in[4];
  const float* w_o    = (const float*)d_in[5];
  const float* b_o    = (const float*)d_in[6];
  float* out = (float*)d_out;

  size_t perbuf_b = (size_t)NMR * CC;               // batched buffer elems
  bool batched = ws_size >= 4 * perbuf_b * sizeof(float);   // 64 MB

  if (batched) {
    float* Qb = (float*)d_ws;
    float* Kb = Qb + perbuf_b;
    float* Vb = Kb + perbuf_b;
    float* at = Vb + perbuf_b;
    gemm_conv_qkv_kernel<<<dim3(NMR/64, QKVC/64), 256, 0, stream>>>(
        x, conv_w, conv_b, w_qkv, b_qkv, Qb, Kb, Vb);
    route_attn_kernel<<<NN*HH*(MM/32), 256, 0, stream>>>(Qb, Kb, Vb, at);
    gemm_out_kernel<<<dim3(NMR/64, CC/64), 256, 0, stream>>>(at, w_o, b_o, out, CC);
  } else {
    size_t perbuf = (size_t)MM * CC;                // per-n fallback (16 MB)
    float* Qb = (float*)d_ws;
    float* Kb = Qb + perbuf;
    float* Vb = Kb + perbuf;
    float* at = Vb + perbuf;
    for (int n = 0; n < NN; ++n) {
      const float* xn = x + (size_t)n*MM*CC;
      gemm_conv_qkv_kernel<<<dim3(MM/64, QKVC/64), 256, 0, stream>>>(
          xn, conv_w, conv_b, w_qkv, b_qkv, Qb, Kb, Vb);
      route_attn_kernel<<<HH*(MM/32), 256, 0, stream>>>(Qb, Kb, Vb, at);
      gemm_out_kernel<<<dim3(MM/64, CC/64), 256, 0, stream>>>(
          at, w_o, b_o, out + (size_t)n*MM*CC, CC);
    }
  }
}

// Round 10
// 880.336 us; speedup vs baseline: 20.6261x; 1.3469x over previous
//
#include <hip/hip_runtime.h>
#include <hip/hip_bf16.h>
#include <math.h>

// Problem constants
#define NN   4
#define MM   2048
#define CC   512
#define HH   8
#define DD   64
#define TK   16
#define NMR  8192      // NN*MM
#define QKVC 1536      // 3*CC

// f32(512**-0.5): NEP50 casts the python-float scale to f32 before the ufunc mul
#define SCALE32 ((float)0.044194173824159216)

typedef unsigned long long u64;
typedef unsigned int u32;

// strict f32 multiply that cannot be contracted into a downstream FMA
__device__ __forceinline__ float fmul_nf(float a, float b) {
  float p = a * b;
  asm("" : "+v"(p));
  return p;
}

// order-preserving f32 -> u32 (monotone for all finite floats)
__device__ __forceinline__ u32 ordf(float f) {
  u32 u = __float_as_uint(f);
  return u ^ (u32)(((int)u >> 31) | 0x80000000);
}
__device__ __forceinline__ float unordf(u32 k) {
  u32 u = (k & 0x80000000u) ? (k ^ 0x80000000u) : ~k;
  return __uint_as_float(u);
}
// packed sort key: hi = ordered value, lo = ~idx  =>  u64 '>' == (v desc, idx asc)
__device__ __forceinline__ u64 packkey(float v, u32 notidx) {
  return ((u64)ordf(v) << 32) | (u64)notidx;
}

// descending compare-swap / select-max on packed keys
#define CSW(a,b) { u64 _x=(a), _y=(b); bool _g = _x < _y; (a) = _g ? _y : _x; (b) = _g ? _x : _y; }
#define CMX(a,b) { if ((a) < (b)) (a) = (b); }

// optimal 19-CS sorting network, 8 elements, descending
#define SORT8(N) \
  CSW(N[0],N[1]); CSW(N[2],N[3]); CSW(N[4],N[5]); CSW(N[6],N[7]); \
  CSW(N[0],N[2]); CSW(N[1],N[3]); CSW(N[4],N[6]); CSW(N[5],N[7]); \
  CSW(N[1],N[2]); CSW(N[5],N[6]); CSW(N[0],N[4]); CSW(N[3],N[7]); \
  CSW(N[1],N[5]); CSW(N[2],N[6]); \
  CSW(N[1],N[4]); CSW(N[3],N[6]); \
  CSW(N[2],N[4]); CSW(N[3],N[5]); \
  CSW(N[3],N[4]);

// bitonic cleanup of a 16-long bitonic sequence -> descending sorted
#define BITONIC16(R) \
  CSW(R[0],R[8]); CSW(R[1],R[9]); CSW(R[2],R[10]); CSW(R[3],R[11]); \
  CSW(R[4],R[12]); CSW(R[5],R[13]); CSW(R[6],R[14]); CSW(R[7],R[15]); \
  CSW(R[0],R[4]); CSW(R[1],R[5]); CSW(R[2],R[6]); CSW(R[3],R[7]); \
  CSW(R[8],R[12]); CSW(R[9],R[13]); CSW(R[10],R[14]); CSW(R[11],R[15]); \
  CSW(R[0],R[2]); CSW(R[1],R[3]); CSW(R[4],R[6]); CSW(R[5],R[7]); \
  CSW(R[8],R[10]); CSW(R[9],R[11]); CSW(R[12],R[14]); CSW(R[13],R[15]); \
  CSW(R[0],R[1]); CSW(R[2],R[3]); CSW(R[4],R[5]); CSW(R[6],R[7]); \
  CSW(R[8],R[9]); CSW(R[10],R[11]); CSW(R[12],R[13]); CSW(R[14],R[15]);

// merge sorted-8 N (desc) into running sorted-16 R (desc), keep top-16 of union
#define MERGE8INTO16(R,N) \
  CMX(R[8],N[7]); CMX(R[9],N[6]); CMX(R[10],N[5]); CMX(R[11],N[4]); \
  CMX(R[12],N[3]); CMX(R[13],N[2]); CMX(R[14],N[1]); CMX(R[15],N[0]); \
  BITONIC16(R);

// ---------------- Kernel 1: conv + QKV GEMM, f32 np-mimicry --------------------------
// x2 = x + (((x[-1]*w0 + x[0]*w1) + x[1]*w2) + cb)   [ufunc order, no FMA]
// q/k/v = x2 @ w_qkv (+bias): f32, sequential k=0..511, FMA per step.  UNCHANGED (r9).
__global__ __launch_bounds__(256) void gemm_conv_qkv_kernel(
    const float* __restrict__ x,
    const float* __restrict__ cw,
    const float* __restrict__ cb,
    const float* __restrict__ wqkv,
    const float* __restrict__ bqkv,
    float* __restrict__ Q, float* __restrict__ K, float* __restrict__ V)
{
  __shared__ float As[16][68];    // [k][row], x2 tile
  __shared__ float Bs[16][68];    // [k][col], weights
  __shared__ float cwb[CC*4];     // [c*4+{0,1,2}]=taps, [c*4+3]=bias

  int tid = threadIdx.x;
  for (int i = tid; i < CC; i += 256) {
    cwb[i*4+0] = cw[i*3+0];
    cwb[i*4+1] = cw[i*3+1];
    cwb[i*4+2] = cw[i*3+2];
    cwb[i*4+3] = cb[i];
  }

  int bm = blockIdx.x, bn = blockIdx.y;
  int tx = tid & 15, ty = tid >> 4;
  int ar = tid >> 2;               // tile row 0..63
  int ak = (tid & 3) << 2;         // k offset 0,4,8,12
  int brow = tid >> 4;             // 0..15
  int bcol = (tid & 15) << 2;      // 0..60
  int row = bm*64 + ar;            // global row
  int m = row & (MM - 1);          // position within sequence (conv boundaries)
  const float* xp = x + (size_t)row*CC;
  const float* wp = wqkv + (size_t)brow*QKVC + bn*64 + bcol;

  float acc[4][4];
  #pragma unroll
  for (int i=0;i<4;i++)
    #pragma unroll
    for (int j=0;j<4;j++) acc[i][j]=0.f;

  for (int kt = 0; kt < CC/16; ++kt) {
    int c0 = kt*16 + ak;
    float4 x0  = *(const float4*)(xp + c0);
    float4 xm1 = make_float4(0.f,0.f,0.f,0.f);
    float4 xp1 = make_float4(0.f,0.f,0.f,0.f);
    if (m > 0)      xm1 = *(const float4*)(xp - CC + c0);
    if (m < MM - 1) xp1 = *(const float4*)(xp + CC + c0);
    float4 wv = *(const float4*)(wp + (size_t)kt*16*QKVC);

    __syncthreads();
    {
      const float xe[4]  = {x0.x,  x0.y,  x0.z,  x0.w};
      const float xme[4] = {xm1.x, xm1.y, xm1.z, xm1.w};
      const float xpe[4] = {xp1.x, xp1.y, xp1.z, xp1.w};
      #pragma unroll
      for (int e = 0; e < 4; ++e) {
        int c = c0 + e;
        float p0 = fmul_nf(xme[e], cwb[c*4+0]);
        float p1 = fmul_nf(xe[e],  cwb[c*4+1]);
        float p2 = fmul_nf(xpe[e], cwb[c*4+2]);
        float s  = p0 + p1;
        s = s + p2;
        s = s + cwb[c*4+3];
        As[ak+e][ar] = xe[e] + s;                 // x2 = x + pos
      }
    }
    *(float4*)&Bs[brow][bcol] = wv;
    __syncthreads();

    #pragma unroll
    for (int kk = 0; kk < 16; ++kk) {
      float4 a4 = *(const float4*)&As[kk][ty<<2];
      float4 b4 = *(const float4*)&Bs[kk][tx<<2];
      const float ae[4] = {a4.x, a4.y, a4.z, a4.w};
      const float be[4] = {b4.x, b4.y, b4.z, b4.w};
      #pragma unroll
      for (int i=0;i<4;i++)
        #pragma unroll
        for (int j=0;j<4;j++)
          acc[i][j] = __builtin_fmaf(ae[i], be[j], acc[i][j]);
    }
  }

  int orow = bm*64 + (ty<<2);
  int seg  = bn >> 3;                       // 0=q, 1=k, 2=v
  float* dst = (seg==0) ? Q : ((seg==1) ? K : V);
  int col  = (bn & 7)*64 + (tx<<2);
  float bb[4];
  #pragma unroll
  for (int j=0;j<4;j++) bb[j] = bqkv[bn*64 + (tx<<2) + j];
  #pragma unroll
  for (int i=0;i<4;i++) {
    float4 o = make_float4(acc[i][0]+bb[0], acc[i][1]+bb[1],
                           acc[i][2]+bb[2], acc[i][3]+bb[3]);
    *(float4*)&dst[(size_t)(orow+i)*CC + col] = o;
  }
}

// ---------------- Kernel 2: f32 logits + top-16 + softmax + V-gather -----------------
// v3: logit math identical to r9 (rolled t4, scalar fmul_nf, sequential adds).
// Selection rebuilt: per tile, sort the 8 new (v,idx) packed-u64 keys (19-CS network)
// and bitonic-merge into the running sorted-16 — replaces the convoyed 15-step
// bubble (~1220 VALU/tile/list -> ~300). Packed key = [ordf(v) : ~idx], so u64 '>'
// is exactly (value desc, index asc) = lax.top_k tie semantics.
__global__ __launch_bounds__(256) void route_attn_kernel(
    const float* __restrict__ Q,
    const float* __restrict__ K,
    const float* __restrict__ V,
    float* __restrict__ attn)
{
  __shared__ float qs[32][68];    // q*scale32 (f32-rounded)
  __shared__ float ks[128][68];   // staged k-tile
  int bq = blockIdx.x;
  int n = bq >> 9, h = (bq >> 6) & 7, qt = bq & 63;
  int tid = threadIdx.x;
  int s = tid & 15, qi = tid >> 4;   // thread owns queries qi and qi+16
  size_t nbase = (size_t)n * MM * CC;

  // stage q tile (32 rows x 16 float4), scale applied once in f32
  #pragma unroll
  for (int rep = 0; rep < 2; ++rep) {
    int idx = tid + (rep<<8);
    int r = idx >> 4, c4 = idx & 15;
    const float* p = Q + nbase + (size_t)(qt*32 + r)*CC + h*DD + (c4<<2);
    float4 v = *(const float4*)p;
    qs[r][(c4<<2)+0] = v.x * SCALE32;
    qs[r][(c4<<2)+1] = v.y * SCALE32;
    qs[r][(c4<<2)+2] = v.z * SCALE32;
    qs[r][(c4<<2)+3] = v.w * SCALE32;
  }

  u64 runA[16], runB[16];
  #pragma unroll
  for (int i=0;i<16;i++){ runA[i]=0ull; runB[i]=0ull; }  // key 0 < any real logit key

  for (int kt = 0; kt < 16; ++kt) {      // 16 tiles x 128 keys
    __syncthreads();
    #pragma unroll
    for (int rep = 0; rep < 8; ++rep) {
      int idx = tid + (rep<<8);          // 0..2047
      int r = idx >> 4, c4 = idx & 15;
      *(float4*)&ks[r][c4<<2] =
          *(const float4*)(K + nbase + (size_t)(kt*128 + r)*CC + h*DD + (c4<<2));
    }
    __syncthreads();

    float accA[8], accB[8];
    #pragma unroll
    for (int j=0;j<8;j++){ accA[j]=0.f; accB[j]=0.f; }

    for (int t4 = 0; t4 < 16; ++t4) {    // rolled: keeps VGPR pressure low
      float4 qa = *(const float4*)&qs[qi][t4<<2];
      float4 qb = *(const float4*)&qs[qi+16][t4<<2];
      #pragma unroll
      for (int j = 0; j < 8; ++j) {
        float4 kv = *(const float4*)&ks[s + (j<<4)][t4<<2];
        // separate mul+add, sequential in t — bit-identical np-einsum chain
        accA[j] = accA[j] + fmul_nf(qa.x, kv.x);
        accA[j] = accA[j] + fmul_nf(qa.y, kv.y);
        accA[j] = accA[j] + fmul_nf(qa.z, kv.z);
        accA[j] = accA[j] + fmul_nf(qa.w, kv.w);
        accB[j] = accB[j] + fmul_nf(qb.x, kv.x);
        accB[j] = accB[j] + fmul_nf(qb.y, kv.y);
        accB[j] = accB[j] + fmul_nf(qb.z, kv.z);
        accB[j] = accB[j] + fmul_nf(qb.w, kv.w);
      }
    }

    // batched selection: pack, sort-8, bitonic-merge into running top-16
    u64 NA[8], NB[8];
    #pragma unroll
    for (int j=0;j<8;j++) {
      u32 ni = ~(u32)(kt*128 + s + (j<<4));
      NA[j] = packkey(accA[j], ni);
      NB[j] = packkey(accB[j], ni);
    }
    SORT8(NA); SORT8(NB);
    MERGE8INTO16(runA, NA);
    MERGE8INTO16(runB, NB);
  }

  // 16-lane butterfly merge + epilogue, list A then list B
  #pragma unroll
  for (int which = 0; which < 2; ++which) {
    u64 lv[16];
    #pragma unroll
    for (int i=0;i<16;i++) lv[i] = which ? runB[i] : runA[i];

    #pragma unroll
    for (int off = 1; off < 16; off <<= 1) {
      u64 nv[16];
      #pragma unroll
      for (int i = 0; i < 16; ++i) {       // half-cleaner: union top-16 multiset
        u64 bv = __shfl_xor(lv[15 - i], off);
        nv[i] = (lv[i] < bv) ? bv : lv[i];
      }
      BITONIC16(nv);                       // bitonic -> sorted desc
      #pragma unroll
      for (int i = 0; i < 16; ++i) lv[i] = nv[i];
    }

    // unpack + softmax (f32, sequential — same as passing r9 chain) + V gather
    float vv0 = unordf((u32)(lv[0] >> 32));   // sorted desc -> max
    float e[16]; float Z = 0.f;
    int ki[16];
    #pragma unroll
    for (int i=0;i<16;i++){
      float vi = unordf((u32)(lv[i] >> 32));
      e[i] = expf(vi - vv0); Z += e[i];
      ki[i] = (int)(~(u32)lv[i]) & (MM - 1);  // masked: can never read wild
    }
    float invZ = 1.f / Z;
    float4 o = make_float4(0.f,0.f,0.f,0.f);
    #pragma unroll
    for (int i=0;i<16;i++) {
      const float* vp = V + nbase + (size_t)ki[i]*CC + h*DD + (s<<2);
      float4 vvv = *(const float4*)vp;
      float w = e[i]*invZ;
      o.x += w*vvv.x; o.y += w*vvv.y; o.z += w*vvv.z; o.w += w*vvv.w;
    }
    int qrow = qt*32 + qi + (which ? 16 : 0);
    *(float4*)&attn[nbase + (size_t)qrow*CC + h*DD + (s<<2)] = o;
  }
}

// ---------------- Kernel 3: f32 GEMM out = attn @ w_o + b_o -> f32 -------------------
__global__ __launch_bounds__(256) void gemm_out_kernel(
    const float* __restrict__ A,
    const float* __restrict__ W,
    const float* __restrict__ bias,
    float* __restrict__ O,
    int ncols)
{
  __shared__ float As[16][68];
  __shared__ float Bs[16][68];
  int tid = threadIdx.x;
  int bm = blockIdx.x, bn = blockIdx.y;
  int tx = tid & 15, ty = tid >> 4;
  int ar = tid >> 2;
  int ak = (tid & 3) << 2;
  int brow = tid >> 4;
  int bcol = (tid & 15) << 2;
  const float* Ap = A + (size_t)(bm*64 + ar)*CC + ak;
  const float* Wp = W + (size_t)brow*ncols + bn*64 + bcol;

  float acc[4][4];
  #pragma unroll
  for (int i=0;i<4;i++)
    #pragma unroll
    for (int j=0;j<4;j++) acc[i][j]=0.f;

  for (int kt = 0; kt < CC/16; ++kt) {
    float4 av = *(const float4*)(Ap + kt*16);
    float4 wv = *(const float4*)(Wp + (size_t)kt*16*ncols);
    __syncthreads();
    As[ak+0][ar]=av.x; As[ak+1][ar]=av.y; As[ak+2][ar]=av.z; As[ak+3][ar]=av.w;
    *(float4*)&Bs[brow][bcol] = wv;
    __syncthreads();
    #pragma unroll
    for (int kk = 0; kk < 16; ++kk) {
      float4 a4 = *(const float4*)&As[kk][ty<<2];
      float4 b4 = *(const float4*)&Bs[kk][tx<<2];
      const float ae[4] = {a4.x, a4.y, a4.z, a4.w};
      const float be[4] = {b4.x, b4.y, b4.z, b4.w};
      #pragma unroll
      for (int i=0;i<4;i++)
        #pragma unroll
        for (int j=0;j<4;j++)
          acc[i][j] = __builtin_fmaf(ae[i], be[j], acc[i][j]);
    }
  }
  int row = bm*64 + (ty<<2);
  int col = bn*64 + (tx<<2);
  float bb[4];
  #pragma unroll
  for (int j=0;j<4;j++) bb[j] = bias[col+j];
  #pragma unroll
  for (int i=0;i<4;i++) {
    float4 o = make_float4(acc[i][0]+bb[0], acc[i][1]+bb[1],
                           acc[i][2]+bb[2], acc[i][3]+bb[3]);
    *(float4*)&O[(size_t)(row+i)*ncols + col] = o;
  }
}

// ---------------- launch --------------------------------------------------------------
extern "C" void kernel_launch(void* const* d_in, const int* in_sizes, int n_in,
                              void* d_out, int out_size, void* d_ws, size_t ws_size,
                              hipStream_t stream) {
  (void)in_sizes; (void)n_in; (void)out_size;
  const float* x      = (const float*)d_in[0];
  const float* conv_w = (const float*)d_in[1];
  const float* conv_b = (const float*)d_in[2];
  const float* w_qkv  = (const float*)d_in[3];
  const float* b_qkv  = (const float*)d_in[4];
  const float* w_o    = (const float*)d_in[5];
  const float* b_o    = (const float*)d_in[6];
  float* out = (float*)d_out;

  size_t perbuf_b = (size_t)NMR * CC;               // batched buffer elems
  bool batched = ws_size >= 4 * perbuf_b * sizeof(float);   // 64 MB

  if (batched) {
    float* Qb = (float*)d_ws;
    float* Kb = Qb + perbuf_b;
    float* Vb = Kb + perbuf_b;
    float* at = Vb + perbuf_b;
    gemm_conv_qkv_kernel<<<dim3(NMR/64, QKVC/64), 256, 0, stream>>>(
        x, conv_w, conv_b, w_qkv, b_qkv, Qb, Kb, Vb);
    route_attn_kernel<<<NN*HH*(MM/32), 256, 0, stream>>>(Qb, Kb, Vb, at);
    gemm_out_kernel<<<dim3(NMR/64, CC/64), 256, 0, stream>>>(at, w_o, b_o, out, CC);
  } else {
    size_t perbuf = (size_t)MM * CC;                // per-n fallback (16 MB)
    float* Qb = (float*)d_ws;
    float* Kb = Qb + perbuf;
    float* Vb = Kb + perbuf;
    float* at = Vb + perbuf;
    for (int n = 0; n < NN; ++n) {
      const float* xn = x + (size_t)n*MM*CC;
      gemm_conv_qkv_kernel<<<dim3(MM/64, QKVC/64), 256, 0, stream>>>(
          xn, conv_w, conv_b, w_qkv, b_qkv, Qb, Kb, Vb);
      route_attn_kernel<<<HH*(MM/32), 256, 0, stream>>>(Qb, Kb, Vb, at);
      gemm_out_kernel<<<dim3(MM/64, CC/64), 256, 0, stream>>>(
          at, w_o, b_o, out + (size_t)n*MM*CC, CC);
    }
  }
}